// Round 7
// baseline (510.775 us; speedup 1.0000x reference)
//
#include <hip/hip_runtime.h>
#include <math.h>

typedef __bf16 bf16_t;
typedef bf16_t bf16x8 __attribute__((ext_vector_type(8)));
typedef float  floatx4 __attribute__((ext_vector_type(4)));

#define MFMA16(a, b, c) __builtin_amdgcn_mfma_f32_16x16x32_bf16((a), (b), (c), 0, 0, 0)

// Problem constants
constexpr int NTOT = 256 * 512;   // 131072 samples
constexpr int CDIM = 256;         // K for all GEMMs

// ws: flat stream of 88 weight tiles in USE ORDER; tile = 16 output cols x 256 k
// in MFMA B-fragment order: tile[ks][lane][j] (8 KB). Wave B-load = contiguous 1 KB.
// NEW ORDER (B1 runs first -- see kernel comment):
//   tiles  0..3  : wb1   (phase B1, groups  0..1)
//   tiles  4..19 : w1a   (phase A,  groups  2..9)
//   tiles 20..51 : w1b   (phase B2, groups 10..25)
//   tiles 52..67 : w2a   (phase C,  groups 26..33)
//   tiles 68..71 : w2b   (phase D,  groups 34..35)
//   tiles 72..87 : wb2a  (phase E,  groups 36..43)
constexpr int N_TILES  = 88;
constexpr int WS_ELEMS = N_TILES * 4096;

// ---------------------------------------------------------------------------
__global__ void prep_weights(const float* __restrict__ w1a, const float* __restrict__ w1b,
                             const float* __restrict__ w2a, const float* __restrict__ w2b,
                             const float* __restrict__ wb1, const float* __restrict__ wb2a,
                             bf16_t* __restrict__ ws) {
  int idx = blockIdx.x * 256 + threadIdx.x;
  if (idx >= WS_ELEMS) return;
  int t   = idx >> 12;       // tile
  int rel = idx & 4095;
  const float* src; int dout; int ct;
  if      (t < 4)  { src = wb1;  dout = 64;  ct = t; }
  else if (t < 20) { src = w1a;  dout = 256; ct = t - 4; }
  else if (t < 52) { src = w1b;  dout = 512; ct = t - 20; }
  else if (t < 68) { src = w2a;  dout = 256; ct = t - 52; }
  else if (t < 72) { src = w2b;  dout = 64;  ct = t - 68; }
  else             { src = wb2a; dout = 256; ct = t - 72; }
  int j    = rel & 7;
  int lane = (rel >> 3) & 63;
  int ks   = rel >> 9;
  int o = ct * 16 + (lane & 15);
  int k = ks * 32 + (lane >> 4) * 8 + j;
  ws[idx] = (bf16_t)src[(size_t)k * dout + o];
}

// async global->LDS, 16 B per lane; LDS dest = wave-uniform base + lane*16
__device__ __forceinline__ void gload_lds16(const bf16_t* g, bf16_t* l) {
  __builtin_amdgcn_global_load_lds(
      (const __attribute__((address_space(1))) unsigned int*)g,
      (__attribute__((address_space(3))) unsigned int*)l, 16, 0, 0);
}

// ---------------------------------------------------------------------------
// rt=2 (32 rows/wave) AT 3 WAVES/SIMD VIA LIVE-RANGE SURGERY (R6 post-mortem).
//
// R6 (16 rows/wave, 4 w/SIMD) hit an LDS-read wall: B-frag reads feed 1 MFMA
// each -> 22.5 MB/CU of ds_read_b128 = 94-110us of the 167us kernel. Reads
// scale as 1/(rows per wave); rows cost 4 regs/row of A-state (shape-
// independent). rt=2 halves LDS reads (11.3 MB/CU, ~55us floor) but R0's
// naive liveness needed ~224 regs -> 2 w/SIMD (and R5's cap-170 spilled 54).
// This version restructures liveness so peak ~164 <= cap 170:
//   1. B1 FIRST (before A): kills the sA+hA+hid-f32 triple overlap.
//   2. hid parked as PACKED BF16 (hidp, 16 regs) except unpacked to f32
//      inside B2 and D where it's accumulated/consumed.
//   3. sA RE-MATERIALIZED from global st (L3-resident) before C and E ->
//      sA dead during B2 and D.
//   Live peaks: B1 ~115 / A-end 64+64+16+~20=164 / B2 ~125 / C-end 164 /
//   D ~115 / E ~90. Margin ~6 regs under cap.
// Geometry: block = 4 waves x 32 rows = 128 rows, grid = 1024.
// __launch_bounds__(256,3) -> 3 waves/EU -> cap 170; 3 blocks/CU resident
// (LDS 46080 x 3 = 138 KB <= 160 KB) = 12 waves/CU.
//
// Tripwire: WRITE_SIZE > 20 MB = spill => revert to R6 structure.
//
// Schedule per group:  __syncthreads(); stage(g+1); compute(g).
// CRITICAL: every register array (sA, hA, hid, hidp, p) indexed ONLY with
// compile-time constants, else LLVM demotes to scratch (131-256 MB WRITE_SIZE
// observed). Hence full unrolling below.
// ---------------------------------------------------------------------------
__global__ __launch_bounds__(256, 3)
void mixing_fused(const float* __restrict__ q,     // [N,8]
                  const float* __restrict__ st,    // [N,256]
                  const bf16_t* __restrict__ W,    // ws (tile stream)
                  const float* __restrict__ b1a, const float* __restrict__ b1b,
                  const float* __restrict__ b2a, const float* __restrict__ b2b,
                  const float* __restrict__ bb1,
                  const float* __restrict__ bb2a,
                  const float* __restrict__ wb2b, const float* __restrict__ bb2b,
                  float* __restrict__ out) {
  __shared__ __align__(16) bf16_t wbuf[2][8192];  // 2 x 16 KB weight groups
  __shared__ __align__(16) bf16_t t_s[4][32][36]; // per-wave bounce (transpose)
  __shared__ __align__(16) float  q_s[4][256];    // per-wave q staging

  const int tid  = threadIdx.x;
  const int wid  = tid >> 6;      // 0..3
  const int lane = tid & 63;
  const int l15  = lane & 15;
  const int quad = lane >> 4;
  const int m0   = blockIdx.x * 128 + wid * 32;

  // wave-cooperative stage of group g (16 KB) into wbuf[g&1]; 4 KB per wave
  auto stage = [&](int g) {
    const bf16_t* src = W + (size_t)g * 8192 + wid * 2048 + lane * 8;
    bf16_t* dst = &wbuf[g & 1][wid * 2048];
#pragma unroll
    for (int i = 0; i < 4; ++i)
      gload_lds16(src + i * 512, dst + i * 512);
  };

  // ---- wave-local q staging ----
  *(float4*)&q_s[wid][lane * 4] = *(const float4*)(q + (size_t)m0 * 8 + lane * 4);

  // ---- st A-fragment (re)load: global f32 (L3-resident) -> bf16 frags ----
  auto loadSA = [&](bf16x8 (&A)[2][8]) {
#pragma unroll
    for (int rt = 0; rt < 2; ++rt) {
      const float* rp = st + (size_t)(m0 + rt * 16 + l15) * CDIM;
#pragma unroll
      for (int ks = 0; ks < 8; ++ks) {
        int k0 = ks * 32 + quad * 8;
        float4 f0 = *(const float4*)(rp + k0);
        float4 f1 = *(const float4*)(rp + k0 + 4);
        bf16x8 v;
        v[0] = (bf16_t)f0.x; v[1] = (bf16_t)f0.y; v[2] = (bf16_t)f0.z; v[3] = (bf16_t)f0.w;
        v[4] = (bf16_t)f1.x; v[5] = (bf16_t)f1.y; v[6] = (bf16_t)f1.z; v[7] = (bf16_t)f1.w;
        A[rt][ks] = v;
      }
    }
  };

  // GEMM: 16-col tile h (0/1) of LDS group buffer `buf`, both row tiles.
  // B-frag read once, shared across rt (the whole point of rt=2).
  auto gemmL = [&](int buf, int h, const bf16x8 (&A)[2][8], floatx4 (&acc)[2]) {
    floatx4 z = {0.f, 0.f, 0.f, 0.f};
    acc[0] = z; acc[1] = z;
#pragma unroll
    for (int kk = 0; kk < 8; ++kk) {
      bf16x8 b = *(const bf16x8*)&wbuf[buf][h * 4096 + kk * 512 + lane * 8];
      acc[0] = MFMA16(A[0][kk], b, acc[0]);
      acc[1] = MFMA16(A[1][kk], b, acc[1]);
    }
  };

  bf16x8 sA[2][8];
  loadSA(sA);

  stage(0);

  // ========= Phase B1 (FIRST): hid = st @ wb1 + bb1   groups 0..1 ===========
  floatx4 hid[2][4];
#pragma unroll
  for (int gg = 0; gg < 2; ++gg) {
    __syncthreads();
    stage(1 + gg);
    const int buf = gg & 1;
#pragma unroll
    for (int h = 0; h < 2; ++h) {
      int et = 2 * gg + h;
      floatx4 acc[2];
      gemmL(buf, h, sA, acc);
      float bias = bb1[et * 16 + l15];
      hid[0][et] = acc[0] + bias;
      hid[1][et] = acc[1] + bias;
    }
  }
  // pack hid -> bf16 (16 regs) so it stays cheap through phase A
  bf16x8 hidp[2][2];
#pragma unroll
  for (int rt = 0; rt < 2; ++rt)
#pragma unroll
    for (int g = 0; g < 2; ++g)
#pragma unroll
      for (int j = 0; j < 8; ++j)
        hidp[rt][g][j] = (bf16_t)hid[rt][g * 2 + (j >> 2)][j & 3];

  // ========= Phase A: H1 = elu(st @ w1a + b1a)   groups 2..9 ================
  bf16x8 hA[2][8];
#pragma unroll
  for (int ks = 0; ks < 8; ++ks) {
    __syncthreads();
    stage(3 + ks);
    const int buf = ks & 1;
#pragma unroll
    for (int h = 0; h < 2; ++h) {
      int ct = 2 * ks + h;
      floatx4 acc[2];
      gemmL(buf, h, sA, acc);
      float bias = b1a[ct * 16 + l15];
#pragma unroll
      for (int rt = 0; rt < 2; ++rt)
#pragma unroll
        for (int i = 0; i < 4; ++i) {
          float v = acc[rt][i] + bias;
          v = v > 0.f ? v : (__expf(v) - 1.f);
          t_s[wid][rt * 16 + quad * 4 + i][h * 16 + l15] = (bf16_t)v;
        }
    }
#pragma unroll
    for (int rt = 0; rt < 2; ++rt)
      hA[rt][ks] = *(const bf16x8*)&t_s[wid][rt * 16 + l15][quad * 8];
  }
  // sA is DEAD from here until the loadSA before phase C (B2 uses hA only).

  // ==== Phase B2: W1 = |H1 @ w1b + b1b|; hid += q.*W1   groups 10..25 ========
  // unpack hid to f32 for accumulation
#pragma unroll
  for (int rt = 0; rt < 2; ++rt)
#pragma unroll
    for (int g = 0; g < 2; ++g)
#pragma unroll
      for (int j = 0; j < 8; ++j)
        hid[rt][g * 2 + (j >> 2)][j & 3] = (float)hidp[rt][g][j];

#pragma unroll 1
  for (int a = 0; a < 8; ++a) {
    float qv[2][4];
#pragma unroll
    for (int rt = 0; rt < 2; ++rt)
#pragma unroll
      for (int i = 0; i < 4; ++i)
        qv[rt][i] = q_s[wid][(rt * 16 + quad * 4 + i) * 8 + a];
#pragma unroll
    for (int g2 = 0; g2 < 2; ++g2) {
      const int idx = a * 2 + g2;          // 0..15
      __syncthreads();
      stage(11 + idx);
      const int buf = g2;                  // (10+idx)&1 == g2
#pragma unroll
      for (int h = 0; h < 2; ++h) {
        int ct = a * 4 + g2 * 2 + h;
        const int et = g2 * 2 + h;         // constant
        floatx4 acc[2];
        gemmL(buf, h, hA, acc);
        float bias = b1b[ct * 16 + l15];
#pragma unroll
        for (int rt = 0; rt < 2; ++rt)
#pragma unroll
          for (int i = 0; i < 4; ++i) {
            float w1v = fabsf(acc[rt][i] + bias);
            hid[rt][et][i] += qv[rt][i] * w1v;
          }
      }
    }
  }
  // relu + repack (hid parked as bf16 through phase C)
#pragma unroll
  for (int rt = 0; rt < 2; ++rt)
#pragma unroll
    for (int g = 0; g < 2; ++g)
#pragma unroll
      for (int j = 0; j < 8; ++j)
        hidp[rt][g][j] = (bf16_t)fmaxf(hid[rt][g * 2 + (j >> 2)][j & 3], 0.f);

  // ========= Phase C: H2 = elu(st @ w2a + b2a)  groups 26..33 ===============
  loadSA(sA);                              // re-materialize (L3-resident st)
#pragma unroll
  for (int ks = 0; ks < 8; ++ks) {
    __syncthreads();
    stage(27 + ks);
    const int buf = ks & 1;
#pragma unroll
    for (int h = 0; h < 2; ++h) {
      int ct = 2 * ks + h;
      floatx4 acc[2];
      gemmL(buf, h, sA, acc);
      float bias = b2a[ct * 16 + l15];
#pragma unroll
      for (int rt = 0; rt < 2; ++rt)
#pragma unroll
        for (int i = 0; i < 4; ++i) {
          float v = acc[rt][i] + bias;
          v = v > 0.f ? v : (__expf(v) - 1.f);
          t_s[wid][rt * 16 + quad * 4 + i][h * 16 + l15] = (bf16_t)v;
        }
    }
#pragma unroll
    for (int rt = 0; rt < 2; ++rt)
      hA[rt][ks] = *(const bf16x8*)&t_s[wid][rt * 16 + l15][quad * 8];
  }
  // sA dead again until the loadSA before phase E.

  // ==== Phase D: W2 = |H2 @ w2b + b2b|; p += hid*W2   groups 34..35 =========
#pragma unroll
  for (int rt = 0; rt < 2; ++rt)
#pragma unroll
    for (int g = 0; g < 2; ++g)
#pragma unroll
      for (int j = 0; j < 8; ++j)
        hid[rt][g * 2 + (j >> 2)][j & 3] = (float)hidp[rt][g][j];

  float p[2][4] = {{0.f, 0.f, 0.f, 0.f}, {0.f, 0.f, 0.f, 0.f}};
#pragma unroll
  for (int gg = 0; gg < 2; ++gg) {
    __syncthreads();
    stage(35 + gg);
    const int buf = gg & 1;
#pragma unroll
    for (int h = 0; h < 2; ++h) {
      int et = 2 * gg + h;
      floatx4 acc[2];
      gemmL(buf, h, hA, acc);
      float bias = b2b[et * 16 + l15];
#pragma unroll
      for (int rt = 0; rt < 2; ++rt)
#pragma unroll
        for (int i = 0; i < 4; ++i) {
          float w2v = fabsf(acc[rt][i] + bias);
          p[rt][i] += hid[rt][et][i] * w2v;
        }
    }
  }

  // == Phase E: HB = elu(st @ wb2a + bb2a); p += HB*wb2b   groups 36..43 =====
  loadSA(sA);                              // re-materialize #2
#pragma unroll 1
  for (int gg = 0; gg < 8; ++gg) {
    __syncthreads();
    if (gg < 7) stage(37 + gg);
    const int buf = gg & 1;
#pragma unroll
    for (int h = 0; h < 2; ++h) {
      int ct = 2 * gg + h;
      floatx4 acc[2];
      gemmL(buf, h, sA, acc);
      float bias = bb2a[ct * 16 + l15];
      float wv   = wb2b[ct * 16 + l15];
#pragma unroll
      for (int rt = 0; rt < 2; ++rt)
#pragma unroll
        for (int i = 0; i < 4; ++i) {
          float v = acc[rt][i] + bias;
          v = v > 0.f ? v : (__expf(v) - 1.f);
          p[rt][i] += v * wv;
        }
    }
  }

  // ======= Reduce over 16 column lanes (same row), store joint output ========
  float bb2 = bb2b[0];
#pragma unroll
  for (int rt = 0; rt < 2; ++rt)
#pragma unroll
    for (int i = 0; i < 4; ++i) {
      float v = p[rt][i];
      v += __shfl_xor(v, 1);
      v += __shfl_xor(v, 2);
      v += __shfl_xor(v, 4);
      v += __shfl_xor(v, 8);
      if (l15 == 0) out[m0 + rt * 16 + quad * 4 + i] = v + bb2;
    }
}

// ---------------------------------------------------------------------------
extern "C" void kernel_launch(void* const* d_in, const int* in_sizes, int n_in,
                              void* d_out, int out_size, void* d_ws, size_t ws_size,
                              hipStream_t stream) {
  const float* q    = (const float*)d_in[0];
  const float* st   = (const float*)d_in[1];
  const float* w1a  = (const float*)d_in[2];
  const float* b1a  = (const float*)d_in[3];
  const float* w1b  = (const float*)d_in[4];
  const float* b1b  = (const float*)d_in[5];
  const float* w2a  = (const float*)d_in[6];
  const float* b2a  = (const float*)d_in[7];
  const float* w2b  = (const float*)d_in[8];
  const float* b2b  = (const float*)d_in[9];
  const float* wb1  = (const float*)d_in[10];
  const float* bb1  = (const float*)d_in[11];
  const float* wb2a = (const float*)d_in[12];
  const float* bb2a = (const float*)d_in[13];
  const float* wb2b = (const float*)d_in[14];
  const float* bb2b = (const float*)d_in[15];
  bf16_t* W = (bf16_t*)d_ws;

  hipLaunchKernelGGL(prep_weights, dim3((WS_ELEMS + 255) / 256), dim3(256), 0, stream,
                     w1a, w1b, w2a, w2b, wb1, wb2a, W);
  hipLaunchKernelGGL(mixing_fused, dim3(NTOT / 128), dim3(256), 0, stream,
                     q, st, W, b1a, b1b, b2a, b2b, bb1, bb2a, wb2b, bb2b, (float*)d_out);
}

// Round 8
// 354.094 us; speedup vs baseline: 1.4425x; 1.4425x over previous
//
#include <hip/hip_runtime.h>
#include <math.h>

typedef __bf16 bf16_t;
typedef bf16_t bf16x8 __attribute__((ext_vector_type(8)));
typedef float  floatx4 __attribute__((ext_vector_type(4)));

#define MFMA16(a, b, c) __builtin_amdgcn_mfma_f32_16x16x32_bf16((a), (b), (c), 0, 0, 0)

// Problem constants
constexpr int NTOT = 256 * 512;   // 131072 samples
constexpr int CDIM = 256;         // K for all GEMMs

// ws: flat stream of 88 weight tiles in USE ORDER; tile = 16 output cols x 256 k
// in MFMA B-fragment order: tile[ks][lane][j] (8 KB). Wave B-load = contiguous 1 KB.
//   tiles  0..15 : w1a   (phase A,  groups  0..7)
//   tiles 16..19 : wb1   (phase B1, groups  8..9)
//   tiles 20..51 : w1b   (phase B2, groups 10..25)
//   tiles 52..67 : w2a   (phase C,  groups 26..33)
//   tiles 68..71 : w2b   (phase D,  groups 34..35)
//   tiles 72..87 : wb2a  (phase E,  groups 36..43)
// Group g = tiles {2g, 2g+1}. Tile 2g (h0) is staged to LDS; tile 2g+1 (h1)
// is consumed DIRECTLY from global (L1/L2-resident) -- see kernel comment.
constexpr int N_TILES  = 88;
constexpr int WS_ELEMS = N_TILES * 4096;

// ---------------------------------------------------------------------------
__global__ void prep_weights(const float* __restrict__ w1a, const float* __restrict__ w1b,
                             const float* __restrict__ w2a, const float* __restrict__ w2b,
                             const float* __restrict__ wb1, const float* __restrict__ wb2a,
                             bf16_t* __restrict__ ws) {
  int idx = blockIdx.x * 256 + threadIdx.x;
  if (idx >= WS_ELEMS) return;
  int t   = idx >> 12;       // tile
  int rel = idx & 4095;
  const float* src; int dout; int ct;
  if      (t < 16) { src = w1a;  dout = 256; ct = t; }
  else if (t < 20) { src = wb1;  dout = 64;  ct = t - 16; }
  else if (t < 52) { src = w1b;  dout = 512; ct = t - 20; }
  else if (t < 68) { src = w2a;  dout = 256; ct = t - 52; }
  else if (t < 72) { src = w2b;  dout = 64;  ct = t - 68; }
  else             { src = wb2a; dout = 256; ct = t - 72; }
  int j    = rel & 7;
  int lane = (rel >> 3) & 63;
  int ks   = rel >> 9;
  int o = ct * 16 + (lane & 15);
  int k = ks * 32 + (lane >> 4) * 8 + j;
  ws[idx] = (bf16_t)src[(size_t)k * dout + o];
}

// async global->LDS, 16 B per lane; LDS dest = wave-uniform base + lane*16
__device__ __forceinline__ void gload_lds16(const bf16_t* g, bf16_t* l) {
  __builtin_amdgcn_global_load_lds(
      (const __attribute__((address_space(1))) unsigned int*)g,
      (__attribute__((address_space(3))) unsigned int*)l, 16, 0, 0);
}

// ---------------------------------------------------------------------------
// R6 STRUCTURE + SPLIT-PIPE B-FEED (R7 post-mortem).
//
// Ledger: R6 (16 rows/wave, 4 w/SIMD, 167us, no spill) is the champion; its
// wall is the LDS read pipe at ~66% of achievable (22.5 MB/CU ds_read_b128
// ~= 110us of 167). Halving reads via 32 rows/wave is register-infeasible:
// R1/R5/R7 all spilled catastrophically (demand > cap by >30 => allocator
// dumps everything; R7's loadSA alone holds 64 transient regs in flight).
//
// This version keeps 16 rows/wave but feeds the two tiles of each group from
// DIFFERENT pipes: tile h0 from LDS (staged, as before), tile h1 streamed
// straight from global into a 32-reg buffer Bd. Effects:
//   - LDS reads halve: 22.5 -> 11.3 MB/CU (~66% -> ~33% busy)
//   - staging volume halves (8 KB/group) -> shorter vmcnt(0) drain/barrier
//   - h1 data is L2-resident (704 KB stream per XCD) and L1-resident within
//     a group (8 KB working set, 12 lockstep waves) -> direct-load latency
//     ~180-225 cyc, covered by issuing Bd at group start, consumed AFTER the
//     full h0 compute (~300+ cyc of ds_read+MFMA+epilogue).
// Cost: Bd = 32 regs -> total demand ~150-160. __launch_bounds__(256,3)
// (cap 170, margin ~15 not -30: qualitatively unlike R7). Occupancy 4 -> 3
// waves/SIMD; R0->R6 measured that step at only ~6%, LDS relief should win.
// LDS/block = wbuf 16K + t_s 4.5K + q_s 2K = 22.5 KB (3 blocks = 69 KB).
//
// Tripwires: WRITE_SIZE > 20 MB = spill => revert to R6 verbatim.
//            FETCH_SIZE > +200 MB = L2 assumption wrong => revert.
//
// Schedule per group: barrier; LDd(g,h1)->Bd; stage(g+1,h0); compute h0
// (LDS); compute h1 (Bd).  Bd issued before stage so its waitcnt does not
// require draining the staging loads.
//
// CRITICAL: every register array (sA, hA, hid, p, Bd) indexed ONLY with
// compile-time constants, else LLVM demotes to scratch (131-256 MB
// WRITE_SIZE observed). Hence full unrolling below.
// ---------------------------------------------------------------------------
__global__ __launch_bounds__(256, 3)
void mixing_fused(const float* __restrict__ q,     // [N,8]
                  const float* __restrict__ st,    // [N,256]
                  const bf16_t* __restrict__ W,    // ws (tile stream)
                  const float* __restrict__ b1a, const float* __restrict__ b1b,
                  const float* __restrict__ b2a, const float* __restrict__ b2b,
                  const float* __restrict__ bb1,
                  const float* __restrict__ bb2a,
                  const float* __restrict__ wb2b, const float* __restrict__ bb2b,
                  float* __restrict__ out) {
  __shared__ __align__(16) bf16_t wbuf[2][4096];  // 2 x 8 KB h0-tile buffers
  __shared__ __align__(16) bf16_t t_s[4][16][36]; // per-wave bounce (transpose)
  __shared__ __align__(16) float  q_s[4][128];    // per-wave q staging

  const int tid  = threadIdx.x;
  const int wid  = tid >> 6;      // 0..3
  const int lane = tid & 63;
  const int l15  = lane & 15;
  const int quad = lane >> 4;
  const int m0   = blockIdx.x * 64 + wid * 16;

  // wave-cooperative stage of group g's h0 tile (8 KB) into wbuf[g&1]
  auto stage = [&](int g) {
    const bf16_t* src = W + (size_t)g * 8192 + wid * 1024 + lane * 8;
    bf16_t* dst = &wbuf[g & 1][wid * 1024];
#pragma unroll
    for (int i = 0; i < 2; ++i)
      gload_lds16(src + i * 512, dst + i * 512);
  };

  // direct global->reg load of group g's h1 tile (8 loads, L1/L2-resident)
  bf16x8 Bd[8];
  auto LDd = [&](int g) {
    const bf16_t* wp = W + (size_t)g * 8192 + 4096 + lane * 8;
#pragma unroll
    for (int kk = 0; kk < 8; ++kk)
      Bd[kk] = *(const bf16x8*)(wp + kk * 512);
  };

  // ---- wave-local q staging (16 rows x 8 = 128 floats) ----
  *(float2*)&q_s[wid][lane * 2] = *(const float2*)(q + (size_t)m0 * 8 + lane * 2);

  // ---- st A-fragments straight from global (coalesced), cvt to bf16 ----
  bf16x8 sA[8];
  {
    const float* rp = st + (size_t)(m0 + l15) * CDIM;
#pragma unroll
    for (int ks = 0; ks < 8; ++ks) {
      int k0 = ks * 32 + quad * 8;
      float4 f0 = *(const float4*)(rp + k0);
      float4 f1 = *(const float4*)(rp + k0 + 4);
      bf16x8 v;
      v[0] = (bf16_t)f0.x; v[1] = (bf16_t)f0.y; v[2] = (bf16_t)f0.z; v[3] = (bf16_t)f0.w;
      v[4] = (bf16_t)f1.x; v[5] = (bf16_t)f1.y; v[6] = (bf16_t)f1.z; v[7] = (bf16_t)f1.w;
      sA[ks] = v;
    }
  }

  // GEMM h0: LDS buffer `buf`; GEMM h1: register buffer Bd.
  auto gemmS = [&](int buf, const bf16x8 (&A)[8], floatx4& acc) {
    floatx4 z = {0.f, 0.f, 0.f, 0.f};
    acc = z;
#pragma unroll
    for (int kk = 0; kk < 8; ++kk) {
      bf16x8 b = *(const bf16x8*)&wbuf[buf][kk * 512 + lane * 8];
      acc = MFMA16(A[kk], b, acc);
    }
  };
  auto gemmR = [&](const bf16x8 (&A)[8], floatx4& acc) {
    floatx4 z = {0.f, 0.f, 0.f, 0.f};
    acc = z;
#pragma unroll
    for (int kk = 0; kk < 8; ++kk)
      acc = MFMA16(A[kk], Bd[kk], acc);
  };

  stage(0);

  bf16x8 hA[8];

  // ========= Phase A: H1 = elu(st @ w1a + b1a)   groups 0..7 (FULL unroll) ===
#pragma unroll
  for (int ks = 0; ks < 8; ++ks) {
    __syncthreads();
    LDd(ks);                 // h1 direct loads first (no stage-drain coupling)
    stage(ks + 1);
    const int buf = ks & 1;
    {
      floatx4 acc;
      gemmS(buf, sA, acc);
      float bias = b1a[(2 * ks) * 16 + l15];
#pragma unroll
      for (int i = 0; i < 4; ++i) {
        float v = acc[i] + bias;
        v = v > 0.f ? v : (__expf(v) - 1.f);
        t_s[wid][quad * 4 + i][l15] = (bf16_t)v;
      }
    }
    {
      floatx4 acc;
      gemmR(sA, acc);
      float bias = b1a[(2 * ks + 1) * 16 + l15];
#pragma unroll
      for (int i = 0; i < 4; ++i) {
        float v = acc[i] + bias;
        v = v > 0.f ? v : (__expf(v) - 1.f);
        t_s[wid][quad * 4 + i][16 + l15] = (bf16_t)v;
      }
    }
    hA[ks] = *(const bf16x8*)&t_s[wid][l15][quad * 8];
  }

  // ========= Phase B1: hidden = st @ wb1 + bb1   groups 8..9 (FULL unroll) ===
  floatx4 hid[4];
#pragma unroll
  for (int gg = 0; gg < 2; ++gg) {
    __syncthreads();
    LDd(8 + gg);
    stage(9 + gg);
    const int buf = gg & 1;
    {
      floatx4 acc;
      gemmS(buf, sA, acc);
      hid[2 * gg] = acc + bb1[(2 * gg) * 16 + l15];
    }
    {
      floatx4 acc;
      gemmR(sA, acc);
      hid[2 * gg + 1] = acc + bb1[(2 * gg + 1) * 16 + l15];
    }
  }

  // ==== Phase B2: W1 = |H1 @ w1b + b1b|; hidden += q.*W1   groups 10..25 =====
  // outer a runtime, inner fully unrolled so et (hid index) is constant.
#pragma unroll 1
  for (int a = 0; a < 8; ++a) {
    float qv[4];
#pragma unroll
    for (int i = 0; i < 4; ++i)
      qv[i] = q_s[wid][(quad * 4 + i) * 8 + a];
#pragma unroll
    for (int g2 = 0; g2 < 2; ++g2) {
      const int idx = a * 2 + g2;          // 0..15
      __syncthreads();
      LDd(10 + idx);
      stage(11 + idx);
      const int buf = g2;                  // (10+idx)&1 == g2
      {
        const int et = g2 * 2;             // constant
        floatx4 acc;
        gemmS(buf, hA, acc);
        float bias = b1b[(a * 4 + g2 * 2) * 16 + l15];
#pragma unroll
        for (int i = 0; i < 4; ++i) {
          float w1v = fabsf(acc[i] + bias);
          hid[et][i] += qv[i] * w1v;
        }
      }
      {
        const int et = g2 * 2 + 1;         // constant
        floatx4 acc;
        gemmR(hA, acc);
        float bias = b1b[(a * 4 + g2 * 2 + 1) * 16 + l15];
#pragma unroll
        for (int i = 0; i < 4; ++i) {
          float w1v = fabsf(acc[i] + bias);
          hid[et][i] += qv[i] * w1v;
        }
      }
    }
  }
  // relu
#pragma unroll
  for (int et = 0; et < 4; ++et)
#pragma unroll
    for (int i = 0; i < 4; ++i) hid[et][i] = fmaxf(hid[et][i], 0.f);

  // ========= Phase C: H2 = elu(st @ w2a + b2a)  groups 26..33 (FULL unroll) ==
#pragma unroll
  for (int ks = 0; ks < 8; ++ks) {
    __syncthreads();
    LDd(26 + ks);
    stage(27 + ks);
    const int buf = ks & 1;
    {
      floatx4 acc;
      gemmS(buf, sA, acc);
      float bias = b2a[(2 * ks) * 16 + l15];
#pragma unroll
      for (int i = 0; i < 4; ++i) {
        float v = acc[i] + bias;
        v = v > 0.f ? v : (__expf(v) - 1.f);
        t_s[wid][quad * 4 + i][l15] = (bf16_t)v;
      }
    }
    {
      floatx4 acc;
      gemmR(sA, acc);
      float bias = b2a[(2 * ks + 1) * 16 + l15];
#pragma unroll
      for (int i = 0; i < 4; ++i) {
        float v = acc[i] + bias;
        v = v > 0.f ? v : (__expf(v) - 1.f);
        t_s[wid][quad * 4 + i][16 + l15] = (bf16_t)v;
      }
    }
    hA[ks] = *(const bf16x8*)&t_s[wid][l15][quad * 8];
  }

  // ==== Phase D: W2 = |H2 @ w2b + b2b|; p += hidden*W2   groups 34..35 ======
  float p[4] = {0.f, 0.f, 0.f, 0.f};
#pragma unroll
  for (int gg = 0; gg < 2; ++gg) {
    __syncthreads();
    LDd(34 + gg);
    stage(35 + gg);
    const int buf = gg & 1;
    {
      const int et = 2 * gg;
      floatx4 acc;
      gemmS(buf, hA, acc);
      float bias = b2b[et * 16 + l15];
#pragma unroll
      for (int i = 0; i < 4; ++i) {
        float w2v = fabsf(acc[i] + bias);
        p[i] += hid[et][i] * w2v;
      }
    }
    {
      const int et = 2 * gg + 1;
      floatx4 acc;
      gemmR(hA, acc);
      float bias = b2b[et * 16 + l15];
#pragma unroll
      for (int i = 0; i < 4; ++i) {
        float w2v = fabsf(acc[i] + bias);
        p[i] += hid[et][i] * w2v;
      }
    }
  }

  // == Phase E: HB = elu(st @ wb2a + bb2a); p += HB*wb2b   groups 36..43 =====
#pragma unroll 1
  for (int gg = 0; gg < 8; ++gg) {
    __syncthreads();
    LDd(36 + gg);
    if (gg < 7) stage(37 + gg);
    const int buf = gg & 1;
    {
      int ct = 2 * gg;
      floatx4 acc;
      gemmS(buf, sA, acc);
      float bias = bb2a[ct * 16 + l15];
      float wv   = wb2b[ct * 16 + l15];
#pragma unroll
      for (int i = 0; i < 4; ++i) {
        float v = acc[i] + bias;
        v = v > 0.f ? v : (__expf(v) - 1.f);
        p[i] += v * wv;
      }
    }
    {
      int ct = 2 * gg + 1;
      floatx4 acc;
      gemmR(sA, acc);
      float bias = bb2a[ct * 16 + l15];
      float wv   = wb2b[ct * 16 + l15];
#pragma unroll
      for (int i = 0; i < 4; ++i) {
        float v = acc[i] + bias;
        v = v > 0.f ? v : (__expf(v) - 1.f);
        p[i] += v * wv;
      }
    }
  }

  // ======= Reduce over 16 column lanes (same row), store joint output ========
  float bb2 = bb2b[0];
#pragma unroll
  for (int i = 0; i < 4; ++i) {
    float v = p[i];
    v += __shfl_xor(v, 1);
    v += __shfl_xor(v, 2);
    v += __shfl_xor(v, 4);
    v += __shfl_xor(v, 8);
    if (l15 == 0) out[m0 + quad * 4 + i] = v + bb2;
  }
}

// ---------------------------------------------------------------------------
extern "C" void kernel_launch(void* const* d_in, const int* in_sizes, int n_in,
                              void* d_out, int out_size, void* d_ws, size_t ws_size,
                              hipStream_t stream) {
  const float* q    = (const float*)d_in[0];
  const float* st   = (const float*)d_in[1];
  const float* w1a  = (const float*)d_in[2];
  const float* b1a  = (const float*)d_in[3];
  const float* w1b  = (const float*)d_in[4];
  const float* b1b  = (const float*)d_in[5];
  const float* w2a  = (const float*)d_in[6];
  const float* b2a  = (const float*)d_in[7];
  const float* w2b  = (const float*)d_in[8];
  const float* b2b  = (const float*)d_in[9];
  const float* wb1  = (const float*)d_in[10];
  const float* bb1  = (const float*)d_in[11];
  const float* wb2a = (const float*)d_in[12];
  const float* bb2a = (const float*)d_in[13];
  const float* wb2b = (const float*)d_in[14];
  const float* bb2b = (const float*)d_in[15];
  bf16_t* W = (bf16_t*)d_ws;

  hipLaunchKernelGGL(prep_weights, dim3((WS_ELEMS + 255) / 256), dim3(256), 0, stream,
                     w1a, w1b, w2a, w2b, wb1, wb2a, W);
  hipLaunchKernelGGL(mixing_fused, dim3(NTOT / 64), dim3(256), 0, stream,
                     q, st, W, b1a, b1b, b2a, b2b, bb1, bb2a, wb2b, bb2b, (float*)d_out);
}